// Round 2
// baseline (475.912 us; speedup 1.0000x reference)
//
#include <hip/hip_runtime.h>

// MinimalThinkingRefiner: out = (mask[b,s]==2) ? x + alpha*(x*scale + shift) : x
// Shapes: x [4,4096,4096] f32, mask [4,4096] i32, scale/shift [4096] f32, alpha f32.
//
// v3 = v2 with the out_size convention fixed: out_size is an ELEMENT count
// (67,108,864 floats), not bytes. v2 divided by 16 and only processed 1/4 of
// the rows (absmax 5.97 = untouched zeros). total4 = out_size/4 = 16,777,216.
//
// Column-persistent mapping:
//  - Each thread owns one fixed col4 (H/4 = 1024 float4 columns); scale/shift
//    are loaded ONCE per thread into registers instead of once per grid-stride
//    iteration (removes 2 of 3 VMEM loads per 16B of x traffic).
//  - Threads march down rows with stride 512 (grid 2048 x 256 = 524288 threads
//    = 512 rows in flight x 1024 cols; 32 iterations each); wave lanes stay
//    contiguous in col4 so every load/store is a coalesced 1KB/wave transaction.
//  - Nontemporal store for out: write-once stream, avoid evicting x
//    (x = 256 MiB = exactly L3 size) from L2/L3.

#define H4 1024  // H / 4

using f4 = __attribute__((ext_vector_type(4))) float;

__global__ __launch_bounds__(256) void MinimalThinkingRefiner_kernel(
    const f4*    __restrict__ x,
    const int*   __restrict__ mask,
    const f4*    __restrict__ scale4,
    const f4*    __restrict__ shift4,
    const float* __restrict__ alpha_p,
    f4*          __restrict__ out,
    int nrows)
{
    const float alpha = *alpha_p;
    const int t       = blockIdx.x * blockDim.x + threadIdx.x;  // 0 .. 524287
    const int col4    = t & (H4 - 1);
    const int row0    = t >> 10;                                // 0 .. 511
    const int rstride = (gridDim.x * blockDim.x) >> 10;         // 512

    // Per-thread invariant: loaded once, live in 8 VGPRs for the whole kernel.
    const f4 sv = scale4[col4];
    const f4 tv = shift4[col4];

    #pragma unroll 4
    for (int row = row0; row < nrows; row += rstride) {
        const int  m = mask[row];            // wave-uniform address -> L1 broadcast
        const long i = (long)row * H4 + col4;
        const f4   xv = x[i];
        f4 o;
        o.x = fmaf(alpha, fmaf(xv.x, sv.x, tv.x), xv.x);
        o.y = fmaf(alpha, fmaf(xv.y, sv.y, tv.y), xv.y);
        o.z = fmaf(alpha, fmaf(xv.z, sv.z, tv.z), xv.z);
        o.w = fmaf(alpha, fmaf(xv.w, sv.w, tv.w), xv.w);
        if (m != 2) o = xv;                  // non-thinking rows pass through
        __builtin_nontemporal_store(o, &out[i]);
    }
}

extern "C" void kernel_launch(void* const* d_in, const int* in_sizes, int n_in,
                              void* d_out, int out_size, void* d_ws, size_t ws_size,
                              hipStream_t stream) {
    const f4*    x     = (const f4*)   d_in[0];
    const int*   mask  = (const int*)  d_in[1];
    const f4*    scale = (const f4*)   d_in[2];
    const f4*    shift = (const f4*)   d_in[3];
    const float* alpha = (const float*)d_in[4];
    f4*          out   = (f4*)d_out;

    const int total4 = out_size / 4;     // out_size is ELEMENT count -> 16,777,216 float4
    const int nrows  = total4 >> 10;     // 16384 rows (B*S)
    const int block  = 256;
    const int grid   = 2048;             // 524288 threads = 512 rows x 1024 cols

    MinimalThinkingRefiner_kernel<<<grid, block, 0, stream>>>(
        x, mask, scale, shift, alpha, out, nrows);
}

// Round 3
// 461.895 us; speedup vs baseline: 1.0303x; 1.0303x over previous
//
#include <hip/hip_runtime.h>

// MinimalThinkingRefiner: out = (mask[b,s]==2) ? x + alpha*(x*scale + shift) : x
// Shapes: x [4,4096,4096] f32, mask [4,4096] i32, scale/shift [4096] f32, alpha f32.
//
// v4 = v3 with the nontemporal store REVERTED. v3 post-mortem: WRITE_SIZE was
// exactly ideal (268 MB) but write BW collapsed to 1.41 TB/s — the nt bit
// bypasses L2, and L2's write-combining/burst-scheduling to HBM is what makes
// streaming stores fast. Plain stores restore it. (L3 is memory-side on MI355X;
// "don't pollute L3" was a wrong model — all traffic passes through it anyway.)
//
// Kept from v3 (the good parts):
//  - Column-persistent mapping: each thread owns one fixed col4; scale/shift
//    loaded ONCE into registers (VMEM loads per 16B of x: 3 -> 1).
//  - 524288 threads = 512 rows x 1024 col4; stride 512 rows, 32 iters/thread;
//    wave lanes contiguous in col4 -> every access is a coalesced 1KB/wave op.
//  - int (not long) flat index: 16384*1024 = 2^24 fits easily in i32.

#define H4 1024  // H / 4

using f4 = __attribute__((ext_vector_type(4))) float;

__global__ __launch_bounds__(256) void MinimalThinkingRefiner_kernel(
    const f4*    __restrict__ x,
    const int*   __restrict__ mask,
    const f4*    __restrict__ scale4,
    const f4*    __restrict__ shift4,
    const float* __restrict__ alpha_p,
    f4*          __restrict__ out,
    int nrows)
{
    const float alpha = *alpha_p;
    const int t       = blockIdx.x * blockDim.x + threadIdx.x;  // 0 .. 524287
    const int col4    = t & (H4 - 1);
    const int row0    = t >> 10;                                // 0 .. 511
    const int rstride = (gridDim.x * blockDim.x) >> 10;         // 512

    // Per-thread invariant: loaded once, live in 8 VGPRs for the whole kernel.
    const f4 sv = scale4[col4];
    const f4 tv = shift4[col4];

    #pragma unroll 4
    for (int row = row0; row < nrows; row += rstride) {
        const int m = mask[row];             // row-uniform -> L1/L2 broadcast
        const int i = row * H4 + col4;       // < 2^24, i32 is plenty
        const f4  xv = x[i];
        f4 o;
        o.x = fmaf(alpha, fmaf(xv.x, sv.x, tv.x), xv.x);
        o.y = fmaf(alpha, fmaf(xv.y, sv.y, tv.y), xv.y);
        o.z = fmaf(alpha, fmaf(xv.z, sv.z, tv.z), xv.z);
        o.w = fmaf(alpha, fmaf(xv.w, sv.w, tv.w), xv.w);
        if (m != 2) o = xv;                  // non-thinking rows pass through
        out[i] = o;
    }
}

extern "C" void kernel_launch(void* const* d_in, const int* in_sizes, int n_in,
                              void* d_out, int out_size, void* d_ws, size_t ws_size,
                              hipStream_t stream) {
    const f4*    x     = (const f4*)   d_in[0];
    const int*   mask  = (const int*)  d_in[1];
    const f4*    scale = (const f4*)   d_in[2];
    const f4*    shift = (const f4*)   d_in[3];
    const float* alpha = (const float*)d_in[4];
    f4*          out   = (f4*)d_out;

    const int total4 = out_size / 4;     // out_size is ELEMENT count -> 16,777,216 float4
    const int nrows  = total4 >> 10;     // 16384 rows (B*S)
    const int block  = 256;
    const int grid   = 2048;             // 524288 threads = 512 rows x 1024 cols

    MinimalThinkingRefiner_kernel<<<grid, block, 0, stream>>>(
        x, mask, scale, shift, alpha, out, nrows);
}

// Round 4
// 434.167 us; speedup vs baseline: 1.0961x; 1.0639x over previous
//
#include <hip/hip_runtime.h>

// MinimalThinkingRefiner: out = (mask[b,s]==2) ? x + alpha*(x*scale + shift) : x
// Shapes: x [4,4096,4096] f32, mask [4,4096] i32, scale/shift [4096] f32, alpha f32.
//
// v5: block-per-rows structure to make the inner loop copy-shaped.
//  - block = 1024 threads = exactly one row of float4 (col4 = threadIdx.x).
//    scale/shift hoisted once into registers (per-thread invariant).
//  - Each block owns 8 consecutive rows (grid 2048 = 16384/8). row index is
//    blockIdx-derived => UNIFORM: mask[row] compiles to s_load (SMEM path,
//    no VMEM issue slot, no L1 port), preloaded for all 8 rows up front.
//  - `m != 2` is a wave-uniform scalar branch (s_cmp + s_cbranch), replacing
//    4x v_cndmask per iteration.
//  - Inner loop per row: 1 global_load_dwordx4 + 1 global_store_dwordx4 per
//    lane — identical VMEM mix to the 6.3 TB/s copy ubench. Full unroll
//    gives 8-deep outstanding loads.

#define H4 1024  // H / 4
#define RPB 8    // rows per block

using f4 = __attribute__((ext_vector_type(4))) float;

__global__ __launch_bounds__(1024) void MinimalThinkingRefiner_kernel(
    const f4*    __restrict__ x,
    const int*   __restrict__ mask,
    const f4*    __restrict__ scale4,
    const f4*    __restrict__ shift4,
    const float* __restrict__ alpha_p,
    f4*          __restrict__ out)
{
    const int tid      = threadIdx.x;           // col4, fixed per thread
    const int row_base = blockIdx.x * RPB;      // uniform

    const float alpha = *alpha_p;
    const f4 sv = scale4[tid];                  // hoisted: 8 VGPRs, loaded once
    const f4 tv = shift4[tid];

    // Uniform addresses -> scalar loads (s_load), SMEM path, issued once.
    int ms[RPB];
    #pragma unroll
    for (int k = 0; k < RPB; ++k) ms[k] = mask[row_base + k];

    #pragma unroll
    for (int k = 0; k < RPB; ++k) {
        const int i  = (row_base + k) * H4 + tid;
        const f4  xv = x[i];
        f4 o = xv;
        if (ms[k] == 2) {                       // wave-uniform scalar branch
            o.x = fmaf(alpha, fmaf(xv.x, sv.x, tv.x), xv.x);
            o.y = fmaf(alpha, fmaf(xv.y, sv.y, tv.y), xv.y);
            o.z = fmaf(alpha, fmaf(xv.z, sv.z, tv.z), xv.z);
            o.w = fmaf(alpha, fmaf(xv.w, sv.w, tv.w), xv.w);
        }
        out[i] = o;
    }
}

extern "C" void kernel_launch(void* const* d_in, const int* in_sizes, int n_in,
                              void* d_out, int out_size, void* d_ws, size_t ws_size,
                              hipStream_t stream) {
    const f4*    x     = (const f4*)   d_in[0];
    const int*   mask  = (const int*)  d_in[1];
    const f4*    scale = (const f4*)   d_in[2];
    const f4*    shift = (const f4*)   d_in[3];
    const float* alpha = (const float*)d_in[4];
    f4*          out   = (f4*)d_out;

    const int total4 = out_size / 4;     // out_size is ELEMENT count -> 16,777,216 float4
    const int nrows  = total4 >> 10;     // 16384 rows (B*S)
    const int grid   = nrows / RPB;      // 2048 blocks x 8 rows
    const int block  = H4;               // 1024 threads = one row of float4

    MinimalThinkingRefiner_kernel<<<grid, block, 0, stream>>>(
        x, mask, scale, shift, alpha, out);
}